// Round 5
// baseline (487.830 us; speedup 1.0000x reference)
//
#include <hip/hip_runtime.h>
#include <hip/hip_fp16.h>

#define DIN 128
#define DOUT 32
#define SLOPE 0.2f

#define BSHIFT 7                 // 128 nodes per bucket
#define BNODES 128
#define NBS    1024              // scan width (>= 782 buckets, pow2)
#define BPITCH 784               // boff row pitch (ints): offs[0..782]
#define CAP    3072              // aggregate LDS capacity (lambda 2046, +22 sigma)
#define TILE   4096              // edges per bin block (391 bin blocks)
#define EPB    (TILE / 256)      // edges per thread (16)

typedef short s16x8 __attribute__((ext_vector_type(8)));   // 8 bf16 (4 VGPRs)
typedef float f32x4 __attribute__((ext_vector_type(4)));   // MFMA C/D frag

__device__ __forceinline__ short f2bf(float f) {          // fp32 -> bf16 (RNE)
    unsigned u = __float_as_uint(f);
    return (short)((u + 0x7fffu + ((u >> 16) & 1u)) >> 16);
}
__device__ __forceinline__ float bf2f(short s) {
    return __uint_as_float(((unsigned)(unsigned short)s) << 16);
}

// ---------------- Linear role: one wave = 16 rows of h via MFMA --------------
// hi/lo bf16 split both sides, 3 MFMAs per tile => fp32-level accuracy.
__device__ __forceinline__ void linear_role(
    int tile, int ntiles, int lane, int N,
    const float* __restrict__ x, const float* __restrict__ W,
    const float* __restrict__ b, const float* __restrict__ a2,
    __half* __restrict__ g16, float* __restrict__ es2)
{
    if (tile >= ntiles) return;
    int m = lane & 15, oct = lane >> 4;
    long rowbase = (long)tile * 16;

    s16x8 bh[2][4], bl[2][4];
    #pragma unroll
    for (int t = 0; t < 2; ++t) {
        const float* wrow = W + (long)(t * 16 + m) * DIN + oct * 8;
        #pragma unroll
        for (int kc = 0; kc < 4; ++kc) {
            float4 w0 = *(const float4*)(wrow + kc * 32);
            float4 w1 = *(const float4*)(wrow + kc * 32 + 4);
            float wf[8] = {w0.x, w0.y, w0.z, w0.w, w1.x, w1.y, w1.z, w1.w};
            #pragma unroll
            for (int j = 0; j < 8; ++j) {
                short hh = f2bf(wf[j]);
                bh[t][kc][j] = hh;
                bl[t][kc][j] = f2bf(wf[j] - bf2f(hh));
            }
        }
    }

    long lrow = rowbase + m; if (lrow > N - 1) lrow = N - 1;   // load clamp
    const float* xrow = x + lrow * DIN + oct * 8;
    f32x4 acc0 = {0.f, 0.f, 0.f, 0.f}, acc1 = {0.f, 0.f, 0.f, 0.f};
    #pragma unroll
    for (int kc = 0; kc < 4; ++kc) {
        float4 x0 = *(const float4*)(xrow + kc * 32);
        float4 x1 = *(const float4*)(xrow + kc * 32 + 4);
        float xf[8] = {x0.x, x0.y, x0.z, x0.w, x1.x, x1.y, x1.z, x1.w};
        s16x8 ah, al;
        #pragma unroll
        for (int j = 0; j < 8; ++j) {
            short hh = f2bf(xf[j]);
            ah[j] = hh;
            al[j] = f2bf(xf[j] - bf2f(hh));
        }
        acc0 = __builtin_amdgcn_mfma_f32_16x16x32_bf16(al, bh[0][kc], acc0, 0, 0, 0);
        acc0 = __builtin_amdgcn_mfma_f32_16x16x32_bf16(ah, bl[0][kc], acc0, 0, 0, 0);
        acc0 = __builtin_amdgcn_mfma_f32_16x16x32_bf16(ah, bh[0][kc], acc0, 0, 0, 0);
        acc1 = __builtin_amdgcn_mfma_f32_16x16x32_bf16(al, bh[1][kc], acc1, 0, 0, 0);
        acc1 = __builtin_amdgcn_mfma_f32_16x16x32_bf16(ah, bl[1][kc], acc1, 0, 0, 0);
        acc1 = __builtin_amdgcn_mfma_f32_16x16x32_bf16(ah, bh[1][kc], acc1, 0, 0, 0);
    }

    int c0 = m, c1 = 16 + m;
    float b0 = b[c0], b1 = b[c1], A0 = a2[c0], A1 = a2[c1];
    float hv0[4], hv1[4], sp[4];
    #pragma unroll
    for (int i = 0; i < 4; ++i) {
        hv0[i] = acc0[i] + b0;
        hv1[i] = acc1[i] + b1;
        float z0 = hv0[i] > 0.f ? hv0[i] : SLOPE * hv0[i];
        float z1 = hv1[i] > 0.f ? hv1[i] : SLOPE * hv1[i];
        sp[i] = z0 * A0 + z1 * A1;
    }
    #pragma unroll
    for (int off = 1; off <= 8; off <<= 1) {
        #pragma unroll
        for (int i = 0; i < 4; ++i) sp[i] += __shfl_xor(sp[i], off, 64);
    }
    #pragma unroll
    for (int i = 0; i < 4; ++i) {
        long r = rowbase + oct * 4 + i;
        if (r >= N) continue;
        float ev = __expf(sp[i]);              // shift-invariant softmax: no max pass
        g16[r * DOUT + c0] = __float2half(ev * hv0[i]);
        g16[r * DOUT + c1] = __float2half(ev * hv1[i]);
        if (m == 0) es2[r] = ev;
    }
}

// ---------------- Fused kernel: bin blocks FIRST, linear blocks fill in ------
// ZERO global atomics (verified R4: fused dropped below the aggregate).
// Each bin block counting-sorts its TILE edges by bucket into its PRIVATE
// slab ebuf[block*TILE ..] and writes the 783-entry bucket offset table
// boff[block][*] with plain coalesced stores.
__global__ __launch_bounds__(256) void gat_fused(
    const float* __restrict__ x, const float* __restrict__ W,
    const float* __restrict__ b, const float* __restrict__ a2,
    const int* __restrict__ src, const int* __restrict__ dst,
    __half* __restrict__ g16, float* __restrict__ es2,
    unsigned* __restrict__ ebuf, int* __restrict__ boff,
    int N, int E, int ntiles, int nbin)
{
    if ((int)blockIdx.x >= nbin) {
        int wave = threadIdx.x >> 6;
        int tile = (blockIdx.x - nbin) * 4 + wave;
        linear_role(tile, ntiles, threadIdx.x & 63, N, x, W, b, a2, g16, es2);
        return;
    }
    __shared__ int cnt[NBS];     // 4 KB (buckets 782..1023 stay zero)
    __shared__ int offs[NBS];    // 4 KB exclusive scan
    __shared__ int wsum[4], wbase[4];
    int tid = threadIdx.x;
    long tstart = (long)blockIdx.x * TILE;

    for (int i = tid; i < NBS; i += 256) cnt[i] = 0;
    __syncthreads();

    unsigned rec[EPB];     // packed record (slot<<17 | dst)
    int      bq[EPB];      // bk<<9 | rank  (per-block per-bucket rank, lambda 5.2)
    #pragma unroll
    for (int it = 0; it < EPB; ++it) {         // pass 1: histogram + rank
        long e = tstart + it * 256 + tid;
        int s = (e < E) ? src[e] : -1;
        int d = (e < E) ? dst[e] : 0;          // prefetch (latency hides here)
        if (s >= 0) {
            int bk = s >> BSHIFT;
            int rv = atomicAdd(&cnt[bk], 1);   // native ds_add_rtn_u32
            rec[it] = ((unsigned)(s & (BNODES - 1)) << 17) | (unsigned)d;
            bq[it] = (rv < 511) ? ((bk << 9) | rv) : -1;   // 9-bit rank: +30 sigma
        } else bq[it] = -1;
    }
    __syncthreads();

    // block-local exclusive scan of cnt[0..1023]: 4 slots/thread + wave scan
    int t4 = tid << 2;
    int c0 = cnt[t4], c1 = cnt[t4 + 1], c2 = cnt[t4 + 2], c3 = cnt[t4 + 3];
    int s4 = c0 + c1 + c2 + c3;
    int v = s4;
    #pragma unroll
    for (int off = 1; off < 64; off <<= 1) {
        int t = __shfl_up(v, off, 64);
        if ((tid & 63) >= off) v += t;
    }
    if ((tid & 63) == 63) wsum[tid >> 6] = v;
    __syncthreads();
    if (tid == 0) {
        int a = 0;
        #pragma unroll
        for (int w = 0; w < 4; ++w) { wbase[w] = a; a += wsum[w]; }
    }
    __syncthreads();
    int base = wbase[tid >> 6] + (v - s4);
    offs[t4]     = base;
    offs[t4 + 1] = base + c0;
    offs[t4 + 2] = base + c0 + c1;
    offs[t4 + 3] = base + c0 + c1 + c2;
    __syncthreads();

    for (int i = tid; i < BPITCH - 1; i += 256)       // coalesced table write
        boff[(size_t)blockIdx.x * BPITCH + i] = offs[i];
    if (tid == 0)                                      // total (= offs[782])
        boff[(size_t)blockIdx.x * BPITCH + BPITCH - 1] = offs[BPITCH - 1];

    #pragma unroll
    for (int it = 0; it < EPB; ++it) {         // pass 2: slab scatter (16KB window)
        int q = bq[it];
        if (q >= 0) {
            int pos = offs[q >> 9] + (q & 511);
            ebuf[tstart + pos] = rec[it];
        }
    }
}

// ---------------- Aggregate: direct native-fp32-LDS accumulation -------------
// One 512-thread block per bucket, XCD-chunked bucket swizzle (consecutive
// buckets share an XCD L2 -> adjacent boff columns / slab runs share lines).
// Pack the nbin per-block runs into rs[] (unchanged, minus the histogram),
// then 16 units x 32 lanes stream records with 8-way independent gathers and
// accumulate via unsafeAtomicAdd -> native ds_add_f32 (NOT plain atomicAdd,
// which compiles to a CAS loop and cost 7x in R3). acc bank = col = lane ->
// 2 lanes/bank per wave = conflict-free. No histogram, no 14-barrier scan,
// no scatter pass, no segmented walk.
__global__ __launch_bounds__(512) void gat_aggregate(
    const __half* __restrict__ g16, const float* __restrict__ es2,
    const unsigned* __restrict__ ebuf, const int* __restrict__ boff,
    float* __restrict__ out, int N, int nbin)
{
    __shared__ unsigned rs[CAP];          // 12 KB packed records
    __shared__ float acc[BNODES][DOUT];   // 16 KB
    __shared__ float den[BNODES];
    __shared__ int wsum[8], wbase[8], totsh;
    int tid = threadIdx.x;

    // bijective XCD-chunked swizzle (m204): XCD k owns a contiguous bk range
    int nwg = gridDim.x;
    int xcd = blockIdx.x & 7;
    int q = nwg >> 3, rr = nwg & 7;
    int bk = (xcd < rr ? xcd * (q + 1) : rr * (q + 1) + (xcd - rr) * q)
           + ((int)blockIdx.x >> 3);

    for (int i = tid; i < BNODES * DOUT; i += 512) ((float*)acc)[i] = 0.f;
    if (tid < BNODES) den[tid] = 0.f;

    // per-block run for this bucket: [boff[b][bk], boff[b][bk+1])
    int rstart = 0, rlen = 0;
    if (tid < nbin) {
        const int* row = boff + (size_t)tid * BPITCH + bk;
        rstart = row[0];
        rlen   = row[1] - rstart;
    }
    int v = rlen;                                    // scan run lengths
    #pragma unroll
    for (int off = 1; off < 64; off <<= 1) {
        int t = __shfl_up(v, off, 64);
        if ((tid & 63) >= off) v += t;
    }
    if ((tid & 63) == 63) wsum[tid >> 6] = v;
    __syncthreads();                                 // also covers acc/den zero
    if (tid == 0) {
        int a = 0;
        #pragma unroll
        for (int w = 0; w < 8; ++w) { wbase[w] = a; a += wsum[w]; }
        totsh = a;
    }
    __syncthreads();
    int dest = wbase[tid >> 6] + (v - rlen);         // exclusive pack offset
    int lim = CAP - dest; if (lim < 0) lim = 0;      // defensive (never fires)
    if (rlen > lim) rlen = lim;
    {
        const unsigned* seg = ebuf + (size_t)tid * TILE + rstart;
        for (int j = 0; j < rlen; ++j)               // pack runs (coalesced-ish)
            rs[dest + j] = seg[j];
    }
    __syncthreads();
    int cntb = totsh; if (cntb > CAP) cntb = CAP;

    int unit = tid >> 5, col = tid & 31;             // 16 units x 32 lanes
    {
        int r    = (cntb * unit) >> 4;               // contiguous slice per unit
        int rend = (cntb * (unit + 1)) >> 4;

        while (r + 8 <= rend) {                      // 8-way independent gathers
            unsigned uu[8];
            #pragma unroll
            for (int j = 0; j < 8; ++j) uu[j] = rs[r + j];        // LDS broadcast
            int dn[8], sl[8];
            #pragma unroll
            for (int j = 0; j < 8; ++j) { dn[j] = (int)(uu[j] & 0x1FFFFu);
                                          sl[j] = (int)(uu[j] >> 17); }
            unsigned short gv[8];
            #pragma unroll
            for (int j = 0; j < 8; ++j)
                gv[j] = *(const unsigned short*)&g16[(long)dn[j] * DOUT + col];
            float ev[8];
            if (col == 0) {
                #pragma unroll
                for (int j = 0; j < 8; ++j) ev[j] = es2[dn[j]];
            }
            #pragma unroll
            for (int j = 0; j < 8; ++j)
                unsafeAtomicAdd(&acc[sl[j]][col],
                                __half2float(*(const __half*)&gv[j]));
            if (col == 0) {
                #pragma unroll
                for (int j = 0; j < 8; ++j) unsafeAtomicAdd(&den[sl[j]], ev[j]);
            }
            r += 8;
        }
        for (; r < rend; ++r) {                      // scalar tail (<=7)
            unsigned u = rs[r];
            int dn = (int)(u & 0x1FFFFu), sl = (int)(u >> 17);
            unsafeAtomicAdd(&acc[sl][col],
                            __half2float(g16[(long)dn * DOUT + col]));
            if (col == 0) unsafeAtomicAdd(&den[sl], es2[dn]);
        }
    }
    __syncthreads();

    for (int sl = unit; sl < BNODES; sl += 16) {     // epilogue: add self, divide
        long node = (long)bk * BNODES + sl;
        if (node >= N) break;
        float self = __half2float(g16[node * DOUT + col]);
        float dsum = den[sl] + es2[node];
        out[node * DOUT + col] = (acc[sl][col] + self) / dsum;
    }
}

extern "C" void kernel_launch(void* const* d_in, const int* in_sizes, int n_in,
                              void* d_out, int out_size, void* d_ws, size_t ws_size,
                              hipStream_t stream)
{
    const float* x  = (const float*)d_in[0];
    const int*   ei = (const int*)d_in[1];
    const float* W  = (const float*)d_in[2];
    const float* b  = (const float*)d_in[3];
    // d_in[4] = a1_w: unused — s1 cancels inside the segment softmax.
    const float* a2 = (const float*)d_in[5];
    float* out = (float*)d_out;

    int N = in_sizes[0] / DIN;
    int E = in_sizes[1] / 2;
    const int* src = ei;
    const int* dst = ei + E;

    int NB = (N + BNODES - 1) >> BSHIFT;      // 782
    int nbin = (E + TILE - 1) / TILE;         // 391 bin blocks

    char* ws = (char*)d_ws;
    __half*   g16  = (__half*)ws;   ws += (size_t)N * DOUT * sizeof(__half);
    float*    es2  = (float*)ws;    ws += (size_t)N * sizeof(float);
    int*      boff = (int*)ws;      ws += (size_t)nbin * BPITCH * sizeof(int);
    unsigned* ebuf = (unsigned*)ws; ws += (size_t)nbin * TILE * sizeof(unsigned);

    int ntiles = (N + 15) / 16;               // 6250
    int nlin   = (ntiles + 3) / 4;            // 1563 linear blocks (4 waves)

    gat_fused    <<<nbin + nlin, 256, 0, stream>>>(x, W, b, a2, src, dst,
                                                   g16, es2, ebuf, boff,
                                                   N, E, ntiles, nbin);
    gat_aggregate<<<NB, 512, 0, stream>>>(g16, es2, ebuf, boff, out, N, nbin);
}

// Round 6
// 157.216 us; speedup vs baseline: 3.1029x; 3.1029x over previous
//
#include <hip/hip_runtime.h>
#include <hip/hip_fp16.h>

#define DIN 128
#define DOUT 32
#define SLOPE 0.2f

#define BSHIFT 7                 // 128 nodes per bucket
#define BNODES 128
#define NBS    1024              // scan width (>= 782 buckets, pow2)
#define BPITCH 784               // boff row pitch (ints): offs[0..783]
#define CAP    3072              // aggregate LDS capacity (lambda 2046, +22 sigma)
#define TILE   4096              // edges per bin block (391 bin blocks)
#define EPB    (TILE / 256)      // edges per thread (16)
#define TPW    4                 // row-tiles per linear wave (W converted once)

typedef short s16x8 __attribute__((ext_vector_type(8)));   // 8 bf16 (4 VGPRs)
typedef float f32x4 __attribute__((ext_vector_type(4)));   // MFMA C/D frag

__device__ __forceinline__ short f2bf(float f) {          // fp32 -> bf16 (RNE)
    unsigned u = __float_as_uint(f);
    return (short)((u + 0x7fffu + ((u >> 16) & 1u)) >> 16);
}
__device__ __forceinline__ float bf2f(short s) {
    return __uint_as_float(((unsigned)(unsigned short)s) << 16);
}

// ---------------- Linear role: one wave = TPW x 16 rows of h via MFMA --------
// W is loaded + hi/lo-bf16-split ONCE per wave, then reused across TPW
// row-tiles (R4 paid this 12K-VALU-op conversion per 16-row tile; this was
// the bulk of fused's VALU time). hi/lo split both sides, 3 MFMAs per
// k-chunk => fp32-level accuracy.
__device__ __forceinline__ void linear_role(
    int wid, int ntiles, int lane, int N,
    const float* __restrict__ x, const float* __restrict__ W,
    const float* __restrict__ b, const float* __restrict__ a2,
    __half* __restrict__ g16, float* __restrict__ es2)
{
    if (wid * TPW >= ntiles) return;
    int m = lane & 15, oct = lane >> 4;

    s16x8 bh[2][4], bl[2][4];
    #pragma unroll
    for (int t = 0; t < 2; ++t) {
        const float* wrow = W + (long)(t * 16 + m) * DIN + oct * 8;
        #pragma unroll
        for (int kc = 0; kc < 4; ++kc) {
            float4 w0 = *(const float4*)(wrow + kc * 32);
            float4 w1 = *(const float4*)(wrow + kc * 32 + 4);
            float wf[8] = {w0.x, w0.y, w0.z, w0.w, w1.x, w1.y, w1.z, w1.w};
            #pragma unroll
            for (int j = 0; j < 8; ++j) {
                short hh = f2bf(wf[j]);
                bh[t][kc][j] = hh;
                bl[t][kc][j] = f2bf(wf[j] - bf2f(hh));
            }
        }
    }

    int c0 = m, c1 = 16 + m;
    float b0 = b[c0], b1 = b[c1], A0 = a2[c0], A1 = a2[c1];

    #pragma unroll 1                           // sequential: keep VGPRs flat
    for (int g = 0; g < TPW; ++g) {
        int tile = wid * TPW + g;
        if (tile >= ntiles) break;
        long rowbase = (long)tile * 16;

        long lrow = rowbase + m; if (lrow > N - 1) lrow = N - 1;   // load clamp
        const float* xrow = x + lrow * DIN + oct * 8;
        f32x4 acc0 = {0.f, 0.f, 0.f, 0.f}, acc1 = {0.f, 0.f, 0.f, 0.f};
        #pragma unroll
        for (int kc = 0; kc < 4; ++kc) {
            float4 x0 = *(const float4*)(xrow + kc * 32);
            float4 x1 = *(const float4*)(xrow + kc * 32 + 4);
            float xf[8] = {x0.x, x0.y, x0.z, x0.w, x1.x, x1.y, x1.z, x1.w};
            s16x8 ah, al;
            #pragma unroll
            for (int j = 0; j < 8; ++j) {
                short hh = f2bf(xf[j]);
                ah[j] = hh;
                al[j] = f2bf(xf[j] - bf2f(hh));
            }
            acc0 = __builtin_amdgcn_mfma_f32_16x16x32_bf16(al, bh[0][kc], acc0, 0, 0, 0);
            acc0 = __builtin_amdgcn_mfma_f32_16x16x32_bf16(ah, bl[0][kc], acc0, 0, 0, 0);
            acc0 = __builtin_amdgcn_mfma_f32_16x16x32_bf16(ah, bh[0][kc], acc0, 0, 0, 0);
            acc1 = __builtin_amdgcn_mfma_f32_16x16x32_bf16(al, bh[1][kc], acc1, 0, 0, 0);
            acc1 = __builtin_amdgcn_mfma_f32_16x16x32_bf16(ah, bl[1][kc], acc1, 0, 0, 0);
            acc1 = __builtin_amdgcn_mfma_f32_16x16x32_bf16(ah, bh[1][kc], acc1, 0, 0, 0);
        }

        float hv0[4], hv1[4], sp[4];
        #pragma unroll
        for (int i = 0; i < 4; ++i) {
            hv0[i] = acc0[i] + b0;
            hv1[i] = acc1[i] + b1;
            float z0 = hv0[i] > 0.f ? hv0[i] : SLOPE * hv0[i];
            float z1 = hv1[i] > 0.f ? hv1[i] : SLOPE * hv1[i];
            sp[i] = z0 * A0 + z1 * A1;
        }
        #pragma unroll
        for (int off = 1; off <= 8; off <<= 1) {
            #pragma unroll
            for (int i = 0; i < 4; ++i) sp[i] += __shfl_xor(sp[i], off, 64);
        }
        #pragma unroll
        for (int i = 0; i < 4; ++i) {
            long r = rowbase + oct * 4 + i;
            if (r >= N) continue;
            float ev = __expf(sp[i]);          // shift-invariant softmax: no max pass
            g16[r * DOUT + c0] = __float2half(ev * hv0[i]);
            g16[r * DOUT + c1] = __float2half(ev * hv1[i]);
            if (m == 0) es2[r] = ev;
        }
    }
}

// ---------------- Fused kernel: bin blocks FIRST, linear blocks fill in ------
// ZERO global atomics (verified R4). Each bin block counting-sorts its TILE
// edges by bucket into its PRIVATE slab ebuf[block*TILE ..] and writes the
// bucket offset table boff[block][*] with plain coalesced stores.
__global__ __launch_bounds__(256) void gat_fused(
    const float* __restrict__ x, const float* __restrict__ W,
    const float* __restrict__ b, const float* __restrict__ a2,
    const int* __restrict__ src, const int* __restrict__ dst,
    __half* __restrict__ g16, float* __restrict__ es2,
    unsigned* __restrict__ ebuf, int* __restrict__ boff,
    int N, int E, int ntiles, int nbin)
{
    if ((int)blockIdx.x >= nbin) {
        int wave = threadIdx.x >> 6;
        int wid = (blockIdx.x - nbin) * 4 + wave;
        linear_role(wid, ntiles, threadIdx.x & 63, N, x, W, b, a2, g16, es2);
        return;
    }
    __shared__ int cnt[NBS];     // 4 KB (buckets 782..1023 stay zero)
    __shared__ int offs[NBS];    // 4 KB exclusive scan
    __shared__ int wsum[4], wbase[4];
    int tid = threadIdx.x;
    long tstart = (long)blockIdx.x * TILE;

    for (int i = tid; i < NBS; i += 256) cnt[i] = 0;
    __syncthreads();

    unsigned rec[EPB];     // packed record (slot<<17 | dst)
    int      bq[EPB];      // bk<<9 | rank  (per-block per-bucket rank, lambda 5.2)
    #pragma unroll
    for (int it = 0; it < EPB; ++it) {         // pass 1: histogram + rank
        long e = tstart + it * 256 + tid;
        int s = (e < E) ? src[e] : -1;
        int d = (e < E) ? dst[e] : 0;          // prefetch (latency hides here)
        if (s >= 0) {
            int bk = s >> BSHIFT;
            int rv = atomicAdd(&cnt[bk], 1);   // native ds_add_rtn_u32
            rec[it] = ((unsigned)(s & (BNODES - 1)) << 17) | (unsigned)d;
            bq[it] = (rv < 511) ? ((bk << 9) | rv) : -1;   // 9-bit rank: +30 sigma
        } else bq[it] = -1;
    }
    __syncthreads();

    // block-local exclusive scan of cnt[0..1023]: 4 slots/thread + wave scan
    int t4 = tid << 2;
    int c0 = cnt[t4], c1 = cnt[t4 + 1], c2 = cnt[t4 + 2], c3 = cnt[t4 + 3];
    int s4 = c0 + c1 + c2 + c3;
    int v = s4;
    #pragma unroll
    for (int off = 1; off < 64; off <<= 1) {
        int t = __shfl_up(v, off, 64);
        if ((tid & 63) >= off) v += t;
    }
    if ((tid & 63) == 63) wsum[tid >> 6] = v;
    __syncthreads();
    if (tid == 0) {
        int a = 0;
        #pragma unroll
        for (int w = 0; w < 4; ++w) { wbase[w] = a; a += wsum[w]; }
    }
    __syncthreads();
    int base = wbase[tid >> 6] + (v - s4);
    offs[t4]     = base;
    offs[t4 + 1] = base + c0;
    offs[t4 + 2] = base + c0 + c1;
    offs[t4 + 3] = base + c0 + c1 + c2;
    __syncthreads();

    for (int i = tid; i < BPITCH - 1; i += 256)       // coalesced table write
        boff[(size_t)blockIdx.x * BPITCH + i] = offs[i];
    if (tid == 0)                                      // total (= offs[783])
        boff[(size_t)blockIdx.x * BPITCH + BPITCH - 1] = offs[BPITCH - 1];

    #pragma unroll
    for (int it = 0; it < EPB; ++it) {         // pass 2: slab scatter (16KB window)
        int q = bq[it];
        if (q >= 0) {
            int pos = offs[q >> 9] + (q & 511);
            ebuf[tstart + pos] = rec[it];
        }
    }
}

// ---------------- Aggregate: gather runs + LDS counting-sort + accumulate ----
// R4's verified-good pipeline (49us) + R5's XCD-chunked bucket swizzle (the
// one R5 element that worked: FETCH 84->57MB via boff/slab line sharing).
// Pack the nbin per-block runs into rs[] (fusing the node histogram), 128-node
// scan, scatter to node order, 16x32 walk with 8-way independent gathers into
// REGISTERS (fp32 LDS atomics are CAS loops on gfx950 — R3 and R5 both
// proved 7x cost; integer LDS atomics are native ds_add).
__global__ __launch_bounds__(512) void gat_aggregate(
    const __half* __restrict__ g16, const float* __restrict__ es2,
    const unsigned* __restrict__ ebuf, const int* __restrict__ boff,
    float* __restrict__ out, int N, int nbin)
{
    __shared__ unsigned rs[CAP];        // 12 KB packed records
    __shared__ unsigned srt[CAP];       // 12 KB node-sorted dst
    __shared__ int cnt[BNODES];
    __shared__ int sc[BNODES];
    __shared__ int basep[BNODES];
    __shared__ int pos2[BNODES];
    __shared__ int wsum[8], wbase[8], totsh;
    int tid = threadIdx.x;

    // bijective XCD-chunked swizzle (m204): XCD k owns a contiguous bk range
    int nwg = gridDim.x;
    int xcd = blockIdx.x & 7;
    int q = nwg >> 3, rr = nwg & 7;
    int bk = (xcd < rr ? xcd * (q + 1) : rr * (q + 1) + (xcd - rr) * q)
           + ((int)blockIdx.x >> 3);

    if (tid < BNODES) { cnt[tid] = 0; pos2[tid] = 0; }
    __syncthreads();

    // per-block run for this bucket: [boff[b][bk], boff[b][bk+1])
    int rstart = 0, rlen = 0;
    if (tid < nbin) {
        const int* row = boff + (size_t)tid * BPITCH + bk;
        rstart = row[0];
        rlen   = row[1] - rstart;
    }
    int v = rlen;                                    // scan run lengths
    #pragma unroll
    for (int off = 1; off < 64; off <<= 1) {
        int t = __shfl_up(v, off, 64);
        if ((tid & 63) >= off) v += t;
    }
    if ((tid & 63) == 63) wsum[tid >> 6] = v;
    __syncthreads();
    if (tid == 0) {
        int a = 0;
        #pragma unroll
        for (int w = 0; w < 8; ++w) { wbase[w] = a; a += wsum[w]; }
        totsh = a;
    }
    __syncthreads();
    int dest = wbase[tid >> 6] + (v - rlen);         // exclusive pack offset
    int lim = CAP - dest; if (lim < 0) lim = 0;      // defensive (never fires)
    if (rlen > lim) rlen = lim;
    {
        const unsigned* seg = ebuf + (size_t)tid * TILE + rstart;
        for (int j = 0; j < rlen; ++j) {             // copy run + node histogram
            unsigned u = seg[j];
            rs[dest + j] = u;
            atomicAdd(&cnt[u >> 17], 1);             // native ds_add
        }
    }
    __syncthreads();
    int cntb = totsh; if (cntb > CAP) cntb = CAP;

    if (tid < BNODES) sc[tid] = cnt[tid];            // Hillis-Steele scan (128)
    __syncthreads();
    #pragma unroll
    for (int off = 1; off < BNODES; off <<= 1) {
        int t = (tid >= off && tid < BNODES) ? sc[tid - off] : 0;
        __syncthreads();
        if (tid < BNODES) sc[tid] += t;
        __syncthreads();
    }
    if (tid < BNODES) basep[tid] = sc[tid] - cnt[tid];   // exclusive
    __syncthreads();
    for (int r = tid; r < cntb; r += 512) {          // scatter into node order
        unsigned u = rs[r];
        int sl = (int)(u >> 17);
        int p = basep[sl] + atomicAdd(&pos2[sl], 1);
        srt[p] = u & 0x1FFFFu;
    }
    __syncthreads();

    int unit = tid >> 5, col = tid & 31;             // 16 units x 32 lanes
    for (int sl = unit; sl < BNODES; sl += 16) {
        long node = (long)bk * BNODES + sl;
        if (node >= N) break;
        float acc = __half2float(g16[node * DOUT + col]);  // self-loop
        float d = es2[node];
        int e = basep[sl], e_end = basep[sl] + cnt[sl];

        while (e + 8 <= e_end) {                     // 8-way independent gathers
            int dn[8];
            #pragma unroll
            for (int j = 0; j < 8; ++j) dn[j] = (int)srt[e + j];   // LDS broadcast
            unsigned short gv[8];
            #pragma unroll
            for (int j = 0; j < 8; ++j)
                gv[j] = *(const unsigned short*)&g16[(long)dn[j] * DOUT + col];
            float ev[8];
            #pragma unroll
            for (int j = 0; j < 8; ++j) ev[j] = es2[dn[j]];
            #pragma unroll
            for (int j = 0; j < 8; ++j) {
                acc += __half2float(*(const __half*)&gv[j]);
                d += ev[j];
            }
            e += 8;
        }
        while (e + 4 <= e_end) {                     // 4-way tail
            int dn[4];
            #pragma unroll
            for (int j = 0; j < 4; ++j) dn[j] = (int)srt[e + j];
            unsigned short gv[4];
            #pragma unroll
            for (int j = 0; j < 4; ++j)
                gv[j] = *(const unsigned short*)&g16[(long)dn[j] * DOUT + col];
            float ev[4];
            #pragma unroll
            for (int j = 0; j < 4; ++j) ev[j] = es2[dn[j]];
            #pragma unroll
            for (int j = 0; j < 4; ++j) {
                acc += __half2float(*(const __half*)&gv[j]);
                d += ev[j];
            }
            e += 4;
        }
        for (; e < e_end; ++e) {                     // scalar tail (<=3)
            int dn = (int)srt[e];
            acc += __half2float(g16[(long)dn * DOUT + col]);
            d += es2[dn];
        }
        out[node * DOUT + col] = acc / d;
    }
}

extern "C" void kernel_launch(void* const* d_in, const int* in_sizes, int n_in,
                              void* d_out, int out_size, void* d_ws, size_t ws_size,
                              hipStream_t stream)
{
    const float* x  = (const float*)d_in[0];
    const int*   ei = (const int*)d_in[1];
    const float* W  = (const float*)d_in[2];
    const float* b  = (const float*)d_in[3];
    // d_in[4] = a1_w: unused — s1 cancels inside the segment softmax.
    const float* a2 = (const float*)d_in[5];
    float* out = (float*)d_out;

    int N = in_sizes[0] / DIN;
    int E = in_sizes[1] / 2;
    const int* src = ei;
    const int* dst = ei + E;

    int NB = (N + BNODES - 1) >> BSHIFT;      // 782
    int nbin = (E + TILE - 1) / TILE;         // 391 bin blocks

    char* ws = (char*)d_ws;
    __half*   g16  = (__half*)ws;   ws += (size_t)N * DOUT * sizeof(__half);
    float*    es2  = (float*)ws;    ws += (size_t)N * sizeof(float);
    int*      boff = (int*)ws;      ws += (size_t)nbin * BPITCH * sizeof(int);
    unsigned* ebuf = (unsigned*)ws; ws += (size_t)nbin * TILE * sizeof(unsigned);

    int ntiles = (N + 15) / 16;               // 6250
    int nwaves = (ntiles + TPW - 1) / TPW;    // 1563 linear waves
    int nlin   = (nwaves + 3) / 4;            // 391 linear blocks (4 waves)

    gat_fused    <<<nbin + nlin, 256, 0, stream>>>(x, W, b, a2, src, dst,
                                                   g16, es2, ebuf, boff,
                                                   N, E, ntiles, nbin);
    gat_aggregate<<<NB, 512, 0, stream>>>(g16, es2, ebuf, boff, out, N, nbin);
}

// Round 7
// 154.079 us; speedup vs baseline: 3.1661x; 1.0204x over previous
//
#include <hip/hip_runtime.h>
#include <hip/hip_fp16.h>

#define DIN 128
#define DOUT 32
#define SLOPE 0.2f

#define BSHIFT 7                 // 128 nodes per bucket
#define BNODES 128
#define NBS    1024              // scan width (>= 782 buckets, pow2)
#define CAP    3072              // aggregate LDS capacity (lambda 2046, +22 sigma)
#define TILE   4096              // edges per bin block (391 bin blocks)
#define EPB    (TILE / 256)      // edges per thread (16)
#define TPW    4                 // row-tiles per linear wave (W converted once)

typedef short s16x8 __attribute__((ext_vector_type(8)));   // 8 bf16 (4 VGPRs)
typedef float f32x4 __attribute__((ext_vector_type(4)));   // MFMA C/D frag

__device__ __forceinline__ short f2bf(float f) {          // fp32 -> bf16 (RNE)
    unsigned u = __float_as_uint(f);
    return (short)((u + 0x7fffu + ((u >> 16) & 1u)) >> 16);
}
__device__ __forceinline__ float bf2f(short s) {
    return __uint_as_float(((unsigned)(unsigned short)s) << 16);
}

// ---------------- Linear role: one wave = TPW x 16 rows of h via MFMA --------
// W is loaded + hi/lo-bf16-split ONCE per wave, then reused across TPW
// row-tiles. hi/lo split both sides, 3 MFMAs per k-chunk => fp32 accuracy.
__device__ __forceinline__ void linear_role(
    int wid, int ntiles, int lane, int N,
    const float* __restrict__ x, const float* __restrict__ W,
    const float* __restrict__ b, const float* __restrict__ a2,
    __half* __restrict__ g16, float* __restrict__ es2)
{
    if (wid * TPW >= ntiles) return;
    int m = lane & 15, oct = lane >> 4;

    s16x8 bh[2][4], bl[2][4];
    #pragma unroll
    for (int t = 0; t < 2; ++t) {
        const float* wrow = W + (long)(t * 16 + m) * DIN + oct * 8;
        #pragma unroll
        for (int kc = 0; kc < 4; ++kc) {
            float4 w0 = *(const float4*)(wrow + kc * 32);
            float4 w1 = *(const float4*)(wrow + kc * 32 + 4);
            float wf[8] = {w0.x, w0.y, w0.z, w0.w, w1.x, w1.y, w1.z, w1.w};
            #pragma unroll
            for (int j = 0; j < 8; ++j) {
                short hh = f2bf(wf[j]);
                bh[t][kc][j] = hh;
                bl[t][kc][j] = f2bf(wf[j] - bf2f(hh));
            }
        }
    }

    int c0 = m, c1 = 16 + m;
    float b0 = b[c0], b1 = b[c1], A0 = a2[c0], A1 = a2[c1];

    #pragma unroll 1                           // sequential: keep VGPRs flat
    for (int g = 0; g < TPW; ++g) {
        int tile = wid * TPW + g;
        if (tile >= ntiles) break;
        long rowbase = (long)tile * 16;

        long lrow = rowbase + m; if (lrow > N - 1) lrow = N - 1;   // load clamp
        const float* xrow = x + lrow * DIN + oct * 8;
        f32x4 acc0 = {0.f, 0.f, 0.f, 0.f}, acc1 = {0.f, 0.f, 0.f, 0.f};
        #pragma unroll
        for (int kc = 0; kc < 4; ++kc) {
            float4 x0 = *(const float4*)(xrow + kc * 32);
            float4 x1 = *(const float4*)(xrow + kc * 32 + 4);
            float xf[8] = {x0.x, x0.y, x0.z, x0.w, x1.x, x1.y, x1.z, x1.w};
            s16x8 ah, al;
            #pragma unroll
            for (int j = 0; j < 8; ++j) {
                short hh = f2bf(xf[j]);
                ah[j] = hh;
                al[j] = f2bf(xf[j] - bf2f(hh));
            }
            acc0 = __builtin_amdgcn_mfma_f32_16x16x32_bf16(al, bh[0][kc], acc0, 0, 0, 0);
            acc0 = __builtin_amdgcn_mfma_f32_16x16x32_bf16(ah, bl[0][kc], acc0, 0, 0, 0);
            acc0 = __builtin_amdgcn_mfma_f32_16x16x32_bf16(ah, bh[0][kc], acc0, 0, 0, 0);
            acc1 = __builtin_amdgcn_mfma_f32_16x16x32_bf16(al, bh[1][kc], acc1, 0, 0, 0);
            acc1 = __builtin_amdgcn_mfma_f32_16x16x32_bf16(ah, bl[1][kc], acc1, 0, 0, 0);
            acc1 = __builtin_amdgcn_mfma_f32_16x16x32_bf16(ah, bh[1][kc], acc1, 0, 0, 0);
        }

        float hv0[4], hv1[4], sp[4];
        #pragma unroll
        for (int i = 0; i < 4; ++i) {
            hv0[i] = acc0[i] + b0;
            hv1[i] = acc1[i] + b1;
            float z0 = hv0[i] > 0.f ? hv0[i] : SLOPE * hv0[i];
            float z1 = hv1[i] > 0.f ? hv1[i] : SLOPE * hv1[i];
            sp[i] = z0 * A0 + z1 * A1;
        }
        #pragma unroll
        for (int off = 1; off <= 8; off <<= 1) {
            #pragma unroll
            for (int i = 0; i < 4; ++i) sp[i] += __shfl_xor(sp[i], off, 64);
        }
        #pragma unroll
        for (int i = 0; i < 4; ++i) {
            long r = rowbase + oct * 4 + i;
            if (r >= N) continue;
            float ev = __expf(sp[i]);          // shift-invariant softmax: no max pass
            g16[r * DOUT + c0] = __float2half(ev * hv0[i]);
            g16[r * DOUT + c1] = __float2half(ev * hv1[i]);
            if (m == 0) es2[r] = ev;
        }
    }
}

// ---------------- Fused kernel: bin blocks FIRST, linear blocks fill in ------
// ZERO global atomics (verified R4). Each bin block counting-sorts its TILE
// edges by bucket into its PRIVATE slab ebuf[block*TILE ..] and writes the
// offset table TRANSPOSED: boffT[bucket][block]. The transposed layout turns
// the aggregate's run-table read into two coalesced row loads (R6 read 391
// scattered lines per bucket); the scattered store here sits in a phase with
// latency slack.
__global__ __launch_bounds__(256) void gat_fused(
    const float* __restrict__ x, const float* __restrict__ W,
    const float* __restrict__ b, const float* __restrict__ a2,
    const int* __restrict__ src, const int* __restrict__ dst,
    __half* __restrict__ g16, float* __restrict__ es2,
    unsigned* __restrict__ ebuf, int* __restrict__ boffT,
    int N, int E, int ntiles, int nbin, int nbinp)
{
    if ((int)blockIdx.x >= nbin) {
        int wave = threadIdx.x >> 6;
        int wid = (blockIdx.x - nbin) * 4 + wave;
        linear_role(wid, ntiles, threadIdx.x & 63, N, x, W, b, a2, g16, es2);
        return;
    }
    __shared__ int cnt[NBS];     // 4 KB (buckets 782..1023 stay zero)
    __shared__ int offs[NBS];    // 4 KB exclusive scan
    __shared__ int wsum[4], wbase[4];
    int tid = threadIdx.x;
    long tstart = (long)blockIdx.x * TILE;

    for (int i = tid; i < NBS; i += 256) cnt[i] = 0;
    __syncthreads();

    unsigned rec[EPB];     // packed record (slot<<17 | dst)
    int      bq[EPB];      // bk<<9 | rank  (per-block per-bucket rank, lambda 5.2)
    #pragma unroll
    for (int it = 0; it < EPB; ++it) {         // pass 1: histogram + rank
        long e = tstart + it * 256 + tid;
        int s = (e < E) ? src[e] : -1;
        int d = (e < E) ? dst[e] : 0;          // prefetch (latency hides here)
        if (s >= 0) {
            int bk = s >> BSHIFT;
            int rv = atomicAdd(&cnt[bk], 1);   // native ds_add_rtn_u32
            rec[it] = ((unsigned)(s & (BNODES - 1)) << 17) | (unsigned)d;
            bq[it] = (rv < 511) ? ((bk << 9) | rv) : -1;   // 9-bit rank: +30 sigma
        } else bq[it] = -1;
    }
    __syncthreads();

    // block-local exclusive scan of cnt[0..1023]: 4 slots/thread + wave scan
    int t4 = tid << 2;
    int c0 = cnt[t4], c1 = cnt[t4 + 1], c2 = cnt[t4 + 2], c3 = cnt[t4 + 3];
    int s4 = c0 + c1 + c2 + c3;
    int v = s4;
    #pragma unroll
    for (int off = 1; off < 64; off <<= 1) {
        int t = __shfl_up(v, off, 64);
        if ((tid & 63) >= off) v += t;
    }
    if ((tid & 63) == 63) wsum[tid >> 6] = v;
    __syncthreads();
    if (tid == 0) {
        int a = 0;
        #pragma unroll
        for (int w = 0; w < 4; ++w) { wbase[w] = a; a += wsum[w]; }
    }
    __syncthreads();
    int base = wbase[tid >> 6] + (v - s4);
    offs[t4]     = base;
    offs[t4 + 1] = base + c0;
    offs[t4 + 2] = base + c0 + c1;
    offs[t4 + 3] = base + c0 + c1 + c2;
    __syncthreads();

    int NBv = (N + BNODES - 1) >> BSHIFT;             // 782
    for (int i = tid; i <= NBv; i += 256)             // transposed table write
        boffT[(size_t)i * nbinp + blockIdx.x] = offs[i];

    #pragma unroll
    for (int it = 0; it < EPB; ++it) {         // pass 2: slab scatter (16KB window)
        int q = bq[it];
        if (q >= 0) {
            int pos = offs[q >> 9] + (q & 511);
            ebuf[tstart + pos] = rec[it];
        }
    }
}

// ---------------- Aggregate: parallel pack + LDS counting-sort + walk --------
// One 512-thread block per bucket, XCD-chunked bucket swizzle.
// R6's serial per-run pack (max_rlen x ~600cy global-latency chain) is
// replaced by: runs write their GATHER ADDRESSES into srca[] (LDS-only short
// loops), then all 512 threads fetch ebuf[srca[r]] in parallel (6-deep,
// consecutive threads = consecutive run addresses -> coalesced), holding
// records in statically-indexed registers. 128-entry node scan is a single
// wave-shfl scan (was 14-barrier Hillis-Steele). Walk unchanged (verified).
// All LDS atomics INTEGER (fp32 LDS atomics = CAS loops, proven R3/R5).
__global__ __launch_bounds__(512) void gat_aggregate(
    const __half* __restrict__ g16, const float* __restrict__ es2,
    const unsigned* __restrict__ ebuf, const int* __restrict__ boffT,
    float* __restrict__ out, int N, int nbin, int nbinp)
{
    __shared__ unsigned srt[CAP];        // 12 KB node-sorted dst
    __shared__ unsigned srca[CAP];       // 12 KB gather addresses
    __shared__ int cnt[BNODES];
    __shared__ int basep[BNODES];
    __shared__ int pos2[BNODES];
    __shared__ int wsum[8], wbase[8], totsh;
    int tid = threadIdx.x;

    // bijective XCD-chunked swizzle (m204): XCD k owns a contiguous bk range
    int nwg = gridDim.x;
    int xcd = blockIdx.x & 7;
    int q = nwg >> 3, rr = nwg & 7;
    int bk = (xcd < rr ? xcd * (q + 1) : rr * (q + 1) + (xcd - rr) * q)
           + ((int)blockIdx.x >> 3);

    if (tid < BNODES) { cnt[tid] = 0; pos2[tid] = 0; }

    // per-block run for this bucket: two COALESCED boffT row reads
    int rstart = 0, rlen = 0;
    if (tid < nbin) {
        rstart = boffT[(size_t)bk * nbinp + tid];
        rlen   = boffT[(size_t)(bk + 1) * nbinp + tid] - rstart;
    }
    int v = rlen;                                    // scan run lengths
    #pragma unroll
    for (int off = 1; off < 64; off <<= 1) {
        int t = __shfl_up(v, off, 64);
        if ((tid & 63) >= off) v += t;
    }
    if ((tid & 63) == 63) wsum[tid >> 6] = v;
    __syncthreads();
    if (tid == 0) {
        int a = 0;
        #pragma unroll
        for (int w = 0; w < 8; ++w) { wbase[w] = a; a += wsum[w]; }
        totsh = a;
    }
    __syncthreads();
    int dest = wbase[tid >> 6] + (v - rlen);         // exclusive pack offset
    int lim = CAP - dest; if (lim < 0) lim = 0;      // defensive (never fires)
    if (rlen > lim) rlen = lim;
    {
        unsigned abase = (unsigned)tid * TILE + (unsigned)rstart;
        for (int j = 0; j < rlen; ++j)               // LDS-only short loop
            srca[dest + j] = abase + (unsigned)j;
    }
    __syncthreads();
    int cntb = totsh; if (cntb > CAP) cntb = CAP;

    // parallel record fetch (coalesced-by-run) + node histogram
    unsigned held[6];                                // CAP/512 = 6, static idx
    #pragma unroll
    for (int k = 0; k < 6; ++k) {
        int r = tid + (k << 9);
        held[k] = 0xFFFFFFFFu;
        if (r < cntb) held[k] = ebuf[(size_t)srca[r]];
    }
    #pragma unroll
    for (int k = 0; k < 6; ++k) {
        unsigned u = held[k];
        if (u != 0xFFFFFFFFu) atomicAdd(&cnt[u >> 17], 1);   // native ds_add
    }
    __syncthreads();

    if (tid < 64) {                                  // single-wave 128-scan
        int a = cnt[2 * tid], b2 = cnt[2 * tid + 1];
        int s = a + b2;
        int vv = s;
        #pragma unroll
        for (int off = 1; off < 64; off <<= 1) {
            int t = __shfl_up(vv, off, 64);
            if (tid >= off) vv += t;
        }
        int excl = vv - s;
        basep[2 * tid]     = excl;
        basep[2 * tid + 1] = excl + a;
    }
    __syncthreads();

    #pragma unroll
    for (int k = 0; k < 6; ++k) {                    // scatter into node order
        unsigned u = held[k];
        if (u != 0xFFFFFFFFu) {
            int sl = (int)(u >> 17);
            int p = basep[sl] + atomicAdd(&pos2[sl], 1);
            srt[p] = u & 0x1FFFFu;
        }
    }
    __syncthreads();

    int unit = tid >> 5, col = tid & 31;             // 16 units x 32 lanes
    for (int sl = unit; sl < BNODES; sl += 16) {
        long node = (long)bk * BNODES + sl;
        if (node >= N) break;
        float acc = __half2float(g16[node * DOUT + col]);  // self-loop
        float d = es2[node];
        int e = basep[sl], e_end = basep[sl] + cnt[sl];

        while (e + 8 <= e_end) {                     // 8-way independent gathers
            int dn[8];
            #pragma unroll
            for (int j = 0; j < 8; ++j) dn[j] = (int)srt[e + j];   // LDS broadcast
            unsigned short gv[8];
            #pragma unroll
            for (int j = 0; j < 8; ++j)
                gv[j] = *(const unsigned short*)&g16[(long)dn[j] * DOUT + col];
            float ev[8];
            #pragma unroll
            for (int j = 0; j < 8; ++j) ev[j] = es2[dn[j]];
            #pragma unroll
            for (int j = 0; j < 8; ++j) {
                acc += __half2float(*(const __half*)&gv[j]);
                d += ev[j];
            }
            e += 8;
        }
        while (e + 4 <= e_end) {                     // 4-way tail
            int dn[4];
            #pragma unroll
            for (int j = 0; j < 4; ++j) dn[j] = (int)srt[e + j];
            unsigned short gv[4];
            #pragma unroll
            for (int j = 0; j < 4; ++j)
                gv[j] = *(const unsigned short*)&g16[(long)dn[j] * DOUT + col];
            float ev[4];
            #pragma unroll
            for (int j = 0; j < 4; ++j) ev[j] = es2[dn[j]];
            #pragma unroll
            for (int j = 0; j < 4; ++j) {
                acc += __half2float(*(const __half*)&gv[j]);
                d += ev[j];
            }
            e += 4;
        }
        for (; e < e_end; ++e) {                     // scalar tail (<=3)
            int dn = (int)srt[e];
            acc += __half2float(g16[(long)dn * DOUT + col]);
            d += es2[dn];
        }
        out[node * DOUT + col] = acc / d;
    }
}

extern "C" void kernel_launch(void* const* d_in, const int* in_sizes, int n_in,
                              void* d_out, int out_size, void* d_ws, size_t ws_size,
                              hipStream_t stream)
{
    const float* x  = (const float*)d_in[0];
    const int*   ei = (const int*)d_in[1];
    const float* W  = (const float*)d_in[2];
    const float* b  = (const float*)d_in[3];
    // d_in[4] = a1_w: unused — s1 cancels inside the segment softmax.
    const float* a2 = (const float*)d_in[5];
    float* out = (float*)d_out;

    int N = in_sizes[0] / DIN;
    int E = in_sizes[1] / 2;
    const int* src = ei;
    const int* dst = ei + E;

    int NB = (N + BNODES - 1) >> BSHIFT;      // 782
    int nbin = (E + TILE - 1) / TILE;         // 391 bin blocks
    int nbinp = (nbin + 7) & ~7;              // 392 (row pitch, coalescing pad)

    char* ws = (char*)d_ws;
    __half*   g16   = (__half*)ws;  ws += (size_t)N * DOUT * sizeof(__half);
    float*    es2   = (float*)ws;   ws += (size_t)N * sizeof(float);
    int*      boffT = (int*)ws;     ws += (size_t)(NB + 1) * nbinp * sizeof(int);
    unsigned* ebuf  = (unsigned*)ws; ws += (size_t)nbin * TILE * sizeof(unsigned);

    int ntiles = (N + 15) / 16;               // 6250
    int nwaves = (ntiles + TPW - 1) / TPW;    // 1563 linear waves
    int nlin   = (nwaves + 3) / 4;            // 391 linear blocks (4 waves)

    gat_fused    <<<nbin + nlin, 256, 0, stream>>>(x, W, b, a2, src, dst,
                                                   g16, es2, ebuf, boffT,
                                                   N, E, ntiles, nbin, nbinp);
    gat_aggregate<<<NB, 512, 0, stream>>>(g16, es2, ebuf, boffT, out, N,
                                          nbin, nbinp);
}